// Round 4
// baseline (6741.542 us; speedup 1.0000x reference)
//
#include <hip/hip_runtime.h>

#define HDIM 2048
#define TSTEPS 1024
#define NBLK 256
#define NTHR 512

typedef unsigned long long ull;

__device__ __forceinline__ int snake_src(int t) {
    int y = t >> 5, p = t & 31;
    return (y & 1) ? (y * 32 + 31 - p) : t;
}
__device__ __forceinline__ float sigmoid_f(float v) {
    return __builtin_amdgcn_rcpf(1.f + __expf(-v));
}
__device__ __forceinline__ float tanh_f(float v) {
    return 1.f - 2.f * __builtin_amdgcn_rcpf(__expf(2.f * v) + 1.f);
}
__device__ __forceinline__ int P(int i) { return i + (i >> 5); }  // pad 1/32

// ---------------------------------------------------------------------------
// Single persistent kernel. 256 blocks (1/CU) x 512 threads.
// Wave wv (0..7) owns column col = blk*8+wv; lane l owns rows [32l, 32l+32).
// 96 recurrent-weight floats per thread stay in registers.
// Per step: poll 4 tagged slots/thread -> LDS (double-buffered) -> ONE
// barrier -> 96 FMA -> 18 intra-wave shuffles -> per-wave finalize+store.
// Cross-block: tagged {tag,f32} 8B agent-scope atomic slots; 0xAA poison tag
// is negative => never matches, so no workspace init needed.
// ---------------------------------------------------------------------------
__global__ __launch_bounds__(NTHR, 2) void gru_all(
    const float* __restrict__ x,
    const float* __restrict__ We,  const float* __restrict__ be,
    const float* __restrict__ Wir, const float* __restrict__ bir,
    const float* __restrict__ Wiz, const float* __restrict__ biz,
    const float* __restrict__ Win, const float* __restrict__ bin_,
    const float* __restrict__ Whr, const float* __restrict__ Whz,
    const float* __restrict__ Whn, const float* __restrict__ bhn,
    float* __restrict__ out, ull* __restrict__ s0, ull* __restrict__ s1)
{
    const int tid  = threadIdx.x;
    const int blk  = blockIdx.x;
    const int lane = tid & 63;
    const int wv   = tid >> 6;            // 0..7
    const int col  = blk * 8 + wv;
    const int row0 = lane * 32;

    __shared__ float hbuf[2][2112];       // padded full-h copies (double buffer)
    __shared__ float xs_l[TSTEPS];

    // ---- stage snake-ordered x into LDS ----
    for (int i = tid; i < TSTEPS; i += NTHR) xs_l[i] = x[snake_src(i)];

    // ---- recurrent weights into registers (one-time) ----
    float wr[32], wz[32], wn[32];
#pragma unroll
    for (int k = 0; k < 32; ++k) {
        size_t off = (size_t)(row0 + k) * HDIM + col;
        wr[k] = Whr[off];
        wz[k] = Whz[off];
        wn[k] = Whn[off];
    }

    // ---- rank-1 input-path constants for this wave's column ----
    float vrc = 0, vzc = 0, vnc = 0, crc = 0, czc = 0, cnc = 0;
#pragma unroll 8
    for (int k = 0; k < 32; ++k) {
        size_t off = (size_t)(row0 + k) * HDIM + col;
        float we = We[row0 + k], bb = be[row0 + k];
        float w0 = Wir[off], w1 = Wiz[off], w2 = Win[off];
        vrc = fmaf(we, w0, vrc);  crc = fmaf(bb, w0, crc);
        vzc = fmaf(we, w1, vzc);  czc = fmaf(bb, w1, czc);
        vnc = fmaf(we, w2, vnc);  cnc = fmaf(bb, w2, cnc);
    }
#pragma unroll
    for (int m = 1; m < 64; m <<= 1) {
        vrc += __shfl_xor(vrc, m, 64); vzc += __shfl_xor(vzc, m, 64);
        vnc += __shfl_xor(vnc, m, 64); crc += __shfl_xor(crc, m, 64);
        czc += __shfl_xor(czc, m, 64); cnc += __shfl_xor(cnc, m, 64);
    }
    crc += bir[col]; czc += biz[col]; cnc += bin_[col];
    const float bhc = bhn[col];

    __syncthreads();   // xs_l ready

    // ---- step 0: h_0 == 0, fully local; publish h_1 with tag 1 ----
    {
        float x0 = xs_l[0];
        float ar = fmaf(x0, vrc, crc);
        float az = fmaf(x0, vzc, czc);
        float an = fmaf(x0, vnc, cnc);
        float rg = sigmoid_f(ar), zg = sigmoid_f(az);
        float ng = tanh_f(fmaf(rg, bhc, an));
        float h1 = (1.f - zg) * ng;
        if (lane == 0) {
            ull pkt = (1ULL << 32) | (ull)__float_as_uint(h1);
            __hip_atomic_store(&s1[col], pkt, __ATOMIC_RELAXED, __HIP_MEMORY_SCOPE_AGENT);
        }
    }

    const int sbase = tid * 4;                 // this thread's 4 h slots
    const int pwb   = sbase + (sbase >> 5);    // padded LDS write base
    const int prb   = row0 + lane;             // padded read base = 33*lane
    const int pcol  = P(col);

    for (int t = 1; t < TSTEPS; ++t) {
        ull* sin  = (t & 1) ? s1 : s0;
        ull* sout = (t & 1) ? s0 : s1;
        float* hb = hbuf[t & 1];

        // ---- poll tagged slots (data rides inside the 8B atomic) ----
        ull v0, v1, v2, v3;
        for (;;) {
            v0 = __hip_atomic_load(&sin[sbase+0], __ATOMIC_RELAXED, __HIP_MEMORY_SCOPE_AGENT);
            v1 = __hip_atomic_load(&sin[sbase+1], __ATOMIC_RELAXED, __HIP_MEMORY_SCOPE_AGENT);
            v2 = __hip_atomic_load(&sin[sbase+2], __ATOMIC_RELAXED, __HIP_MEMORY_SCOPE_AGENT);
            v3 = __hip_atomic_load(&sin[sbase+3], __ATOMIC_RELAXED, __HIP_MEMORY_SCOPE_AGENT);
            if ((int)(v0 >> 32) == t && (int)(v1 >> 32) == t &&
                (int)(v2 >> 32) == t && (int)(v3 >> 32) == t) break;
        }
        hb[pwb + 0] = __uint_as_float((unsigned)v0);
        hb[pwb + 1] = __uint_as_float((unsigned)v1);
        hb[pwb + 2] = __uint_as_float((unsigned)v2);
        hb[pwb + 3] = __uint_as_float((unsigned)v3);
        __syncthreads();                       // the ONLY barrier per step

        // ---- 96 register-resident FMAs over this lane's 32 rows ----
        float a0 = 0.f, a1 = 0.f, a2 = 0.f;
#pragma unroll
        for (int k = 0; k < 32; ++k) {
            float hv = hb[prb + k];
            a0 = fmaf(hv, wr[k], a0);
            a1 = fmaf(hv, wz[k], a1);
            a2 = fmaf(hv, wn[k], a2);
        }
        // ---- intra-wave reduction (column sum lives in every lane) ----
#pragma unroll
        for (int m = 1; m < 64; m <<= 1) {
            a0 += __shfl_xor(a0, m, 64);
            a1 += __shfl_xor(a1, m, 64);
            a2 += __shfl_xor(a2, m, 64);
        }

        // ---- finalize (uniform across wave; lane 0 stores) ----
        float xt = xs_l[t];
        float ar = fmaf(xt, vrc, crc) + a0;
        float az = fmaf(xt, vzc, czc) + a1;
        float an = fmaf(xt, vnc, cnc);
        float rg = sigmoid_f(ar), zg = sigmoid_f(az);
        float ng = tanh_f(an + rg * (a2 + bhc));
        float hold = hb[pcol];                 // h_t[col], LDS broadcast
        float hnew = (1.f - zg) * ng + zg * hold;
        if (lane == 0) {
            if (t == TSTEPS - 1) {
                out[col] = hnew;
            } else {
                ull pkt = ((ull)(unsigned)(t + 1) << 32) | (ull)__float_as_uint(hnew);
                __hip_atomic_store(&sout[col], pkt, __ATOMIC_RELAXED, __HIP_MEMORY_SCOPE_AGENT);
            }
        }
        // no trailing barrier: double-buffered hbuf makes it unnecessary
    }
}

extern "C" void kernel_launch(void* const* d_in, const int* in_sizes, int n_in,
                              void* d_out, int out_size, void* d_ws, size_t ws_size,
                              hipStream_t stream) {
    const float* x    = (const float*)d_in[0];
    const float* We   = (const float*)d_in[1];
    const float* be   = (const float*)d_in[2];
    const float* Wir  = (const float*)d_in[3];
    const float* bir  = (const float*)d_in[4];
    const float* Wiz  = (const float*)d_in[5];
    const float* biz  = (const float*)d_in[6];
    const float* Win  = (const float*)d_in[7];
    const float* bin_ = (const float*)d_in[8];
    const float* Whr  = (const float*)d_in[9];
    const float* Whz  = (const float*)d_in[10];
    const float* Whn  = (const float*)d_in[11];
    const float* bhn  = (const float*)d_in[12];

    ull* s0 = (ull*)d_ws;          // 2048 slots/buffer, no init needed
    ull* s1 = s0 + HDIM;

    gru_all<<<NBLK, NTHR, 0, stream>>>(x, We, be, Wir, bir, Wiz, biz, Win, bin_,
                                       Whr, Whz, Whn, bhn,
                                       (float*)d_out, s0, s1);
}

// Round 5
// 3003.483 us; speedup vs baseline: 2.2446x; 2.2446x over previous
//
#include <hip/hip_runtime.h>

#define HDIM 2048
#define TSTEPS 1024
#define NBLK 128
#define NTHR 512
#define CPB 16     // columns per block

typedef unsigned long long ull;

__device__ __forceinline__ int snake_src(int t) {
    int y = t >> 5, p = t & 31;
    return (y & 1) ? (y * 32 + 31 - p) : t;
}
__device__ __forceinline__ float sigmoid_f(float v) {
    return __builtin_amdgcn_rcpf(1.f + __expf(-v));
}
__device__ __forceinline__ float tanh_f(float v) {
    return 1.f - 2.f * __builtin_amdgcn_rcpf(__expf(2.f * v) + 1.f);
}
__device__ __forceinline__ int P(int i) { return i + (i >> 5); }  // pad 1/32

// ---------------------------------------------------------------------------
// Persistent kernel. 128 blocks x 512 threads; block owns 16 columns.
// Thread (c = tid&15, rr = tid>>4): column col = blk*16+c, rows [64rr,64rr+64).
// 192 recurrent-weight floats per thread stay register-resident (AGPR/VGPR).
// Per step: throttled poll of 4 tagged slots/thread -> LDS (double-buffered)
// -> BAR1 -> 192 FMA + 2-stage shuffle reduce -> red[] (double-buffered)
// -> BAR2 -> wave 0 finalizes 16 cols + ONE coalesced 128B tagged publish.
// Trailing barrier provably unnecessary (both LDS structures double-buffered;
// any overwrite requires passing a barrier that requires wave 0's arrival,
// which is after wave 0's reads).
// Slots: {tag,f32} 8B agent-scope atomics; 0xAA poison tag is negative =>
// never matches t in [1,1023], so no workspace init needed.
// ---------------------------------------------------------------------------
__global__ __launch_bounds__(NTHR, 2) void gru_all(
    const float* __restrict__ x,
    const float* __restrict__ We,  const float* __restrict__ be,
    const float* __restrict__ Wir, const float* __restrict__ bir,
    const float* __restrict__ Wiz, const float* __restrict__ biz,
    const float* __restrict__ Win, const float* __restrict__ bin_,
    const float* __restrict__ Whr, const float* __restrict__ Whz,
    const float* __restrict__ Whn, const float* __restrict__ bhn,
    float* __restrict__ out, ull* __restrict__ s0, ull* __restrict__ s1)
{
    const int tid  = threadIdx.x;
    const int blk  = blockIdx.x;
    const int lane = tid & 63;
    const int wv   = tid >> 6;            // 0..7
    const int c    = tid & 15;
    const int rr   = tid >> 4;            // 0..31
    const int col  = blk * CPB + c;
    const int row0 = rr * 64;

    __shared__ float hbuf[2][2112];             // padded h copies (double buffer)
    __shared__ float xs_l[TSTEPS];
    __shared__ float redc[8][6][17];            // prologue constants
    __shared__ float red[2][8][3][17];          // per-step partials (double buffer)

    // ---- stage snake-ordered x, and We/be (borrow hbuf) ----
    for (int i = tid; i < TSTEPS; i += NTHR) xs_l[i] = x[snake_src(i)];
    for (int i = tid; i < HDIM; i += NTHR) { hbuf[0][i] = We[i]; hbuf[1][i] = be[i]; }
    __syncthreads();

    // ---- recurrent weights into registers (one-time, stays resident) ----
    float wr[64], wz[64], wn[64];
#pragma unroll
    for (int k = 0; k < 64; ++k) {
        size_t off = (size_t)(row0 + k) * HDIM + col;
        wr[k] = Whr[off];
        wz[k] = Whz[off];
        wn[k] = Whn[off];
    }

    // ---- rank-1 input-path constants for this thread's column ----
    {
        float vr = 0, vz = 0, vn = 0, cr = 0, cz = 0, cn = 0;
#pragma unroll 8
        for (int k = 0; k < 64; ++k) {
            size_t off = (size_t)(row0 + k) * HDIM + col;
            float we = hbuf[0][row0 + k], bb = hbuf[1][row0 + k];
            float w0 = Wir[off], w1 = Wiz[off], w2 = Win[off];
            vr = fmaf(we, w0, vr);  cr = fmaf(bb, w0, cr);
            vz = fmaf(we, w1, vz);  cz = fmaf(bb, w1, cz);
            vn = fmaf(we, w2, vn);  cn = fmaf(bb, w2, cn);
        }
#pragma unroll
        for (int m = 16; m < 64; m <<= 1) {
            vr += __shfl_xor(vr, m, 64); vz += __shfl_xor(vz, m, 64);
            vn += __shfl_xor(vn, m, 64); cr += __shfl_xor(cr, m, 64);
            cz += __shfl_xor(cz, m, 64); cn += __shfl_xor(cn, m, 64);
        }
        if (lane < CPB) {
            redc[wv][0][lane] = vr; redc[wv][1][lane] = vz; redc[wv][2][lane] = vn;
            redc[wv][3][lane] = cr; redc[wv][4][lane] = cz; redc[wv][5][lane] = cn;
        }
    }
    __syncthreads();   // constants ready; hbuf(We/be) free for reuse

    // ---- wave 0 lanes 0..15 own the finalize path for the 16 columns ----
    float vrc = 0, vzc = 0, vnc = 0, crc = 0, czc = 0, cnc = 0, bhc = 0;
    if (wv == 0 && lane < CPB) {
#pragma unroll
        for (int w = 0; w < 8; ++w) {
            vrc += redc[w][0][lane]; vzc += redc[w][1][lane]; vnc += redc[w][2][lane];
            crc += redc[w][3][lane]; czc += redc[w][4][lane]; cnc += redc[w][5][lane];
        }
        crc += bir[col]; czc += biz[col]; cnc += bin_[col];
        bhc = bhn[col];

        // ---- step 0: h_0 == 0, fully local; publish h_1 with tag 1 ----
        float x0 = xs_l[0];
        float ar = fmaf(x0, vrc, crc);
        float az = fmaf(x0, vzc, czc);
        float an = fmaf(x0, vnc, cnc);
        float rg = sigmoid_f(ar), zg = sigmoid_f(az);
        float ng = tanh_f(fmaf(rg, bhc, an));
        float h1 = (1.f - zg) * ng;
        ull pkt = (1ULL << 32) | (ull)__float_as_uint(h1);
        __hip_atomic_store(&s1[col], pkt, __ATOMIC_RELAXED, __HIP_MEMORY_SCOPE_AGENT);
    }

    const int sbase = tid * 4;                 // this thread's 4 h slots
    const int pwb   = sbase + (sbase >> 5);    // padded LDS write base
    const int prb   = 66 * rr;                 // padded read base for rows 64rr..
    const int pcol  = P(col);

    for (int t = 1; t < TSTEPS; ++t) {
        ull* sin  = (t & 1) ? s1 : s0;
        ull* sout = (t & 1) ? s0 : s1;
        float* hb = hbuf[t & 1];

        // ---- throttled poll of tagged slots (data rides in the atomic) ----
        ull v0, v1, v2, v3;
        for (;;) {
            v0 = __hip_atomic_load(&sin[sbase+0], __ATOMIC_RELAXED, __HIP_MEMORY_SCOPE_AGENT);
            v1 = __hip_atomic_load(&sin[sbase+1], __ATOMIC_RELAXED, __HIP_MEMORY_SCOPE_AGENT);
            v2 = __hip_atomic_load(&sin[sbase+2], __ATOMIC_RELAXED, __HIP_MEMORY_SCOPE_AGENT);
            v3 = __hip_atomic_load(&sin[sbase+3], __ATOMIC_RELAXED, __HIP_MEMORY_SCOPE_AGENT);
            if ((int)(v0 >> 32) == t && (int)(v1 >> 32) == t &&
                (int)(v2 >> 32) == t && (int)(v3 >> 32) == t) break;
            __builtin_amdgcn_s_sleep(4);       // ~256 cyc backoff: kill poll flood
        }
        hb[pwb + 0] = __uint_as_float((unsigned)v0);
        hb[pwb + 1] = __uint_as_float((unsigned)v1);
        hb[pwb + 2] = __uint_as_float((unsigned)v2);
        hb[pwb + 3] = __uint_as_float((unsigned)v3);
        __syncthreads();                       // BAR1: h_t staged

        // ---- 192 register-resident FMAs over this thread's 64 rows ----
        float a0 = 0.f, a1 = 0.f, a2 = 0.f;
#pragma unroll
        for (int k = 0; k < 32; ++k) {
            float hv = hb[prb + k];
            a0 = fmaf(hv, wr[k], a0);
            a1 = fmaf(hv, wz[k], a1);
            a2 = fmaf(hv, wn[k], a2);
        }
#pragma unroll
        for (int k = 32; k < 64; ++k) {
            float hv = hb[prb + 1 + k];
            a0 = fmaf(hv, wr[k], a0);
            a1 = fmaf(hv, wz[k], a1);
            a2 = fmaf(hv, wn[k], a2);
        }
        // reduce the 4 row-chunks within the wave (lane bits 4,5)
#pragma unroll
        for (int m = 16; m < 64; m <<= 1) {
            a0 += __shfl_xor(a0, m, 64);
            a1 += __shfl_xor(a1, m, 64);
            a2 += __shfl_xor(a2, m, 64);
        }
        float (*rd)[3][17] = red[t & 1];
        if (lane < CPB) { rd[wv][0][lane] = a0; rd[wv][1][lane] = a1; rd[wv][2][lane] = a2; }
        __syncthreads();                       // BAR2: partials ready

        // ---- wave 0: finalize 16 columns, ONE coalesced tagged publish ----
        if (wv == 0 && lane < CPB) {
            float Sr = 0, Sz = 0, Sn = 0;
#pragma unroll
            for (int w = 0; w < 8; ++w) {
                Sr += rd[w][0][lane]; Sz += rd[w][1][lane]; Sn += rd[w][2][lane];
            }
            float xt = xs_l[t];
            float ar = fmaf(xt, vrc, crc) + Sr;
            float az = fmaf(xt, vzc, czc) + Sz;
            float an = fmaf(xt, vnc, cnc);
            float rg = sigmoid_f(ar), zg = sigmoid_f(az);
            float ng = tanh_f(an + rg * (Sn + bhc));
            float hold = hb[pcol];
            float hnew = (1.f - zg) * ng + zg * hold;
            if (t == TSTEPS - 1) {
                out[col] = hnew;
            } else {
                ull pkt = ((ull)(unsigned)(t + 1) << 32) | (ull)__float_as_uint(hnew);
                __hip_atomic_store(&sout[col], pkt, __ATOMIC_RELAXED, __HIP_MEMORY_SCOPE_AGENT);
            }
        }
        // no trailing barrier: hbuf and red are double-buffered, and any
        // overwrite requires passing a barrier that wave 0 only reaches
        // after its reads of this step's buffers.
    }
}

extern "C" void kernel_launch(void* const* d_in, const int* in_sizes, int n_in,
                              void* d_out, int out_size, void* d_ws, size_t ws_size,
                              hipStream_t stream) {
    const float* x    = (const float*)d_in[0];
    const float* We   = (const float*)d_in[1];
    const float* be   = (const float*)d_in[2];
    const float* Wir  = (const float*)d_in[3];
    const float* bir  = (const float*)d_in[4];
    const float* Wiz  = (const float*)d_in[5];
    const float* biz  = (const float*)d_in[6];
    const float* Win  = (const float*)d_in[7];
    const float* bin_ = (const float*)d_in[8];
    const float* Whr  = (const float*)d_in[9];
    const float* Whz  = (const float*)d_in[10];
    const float* Whn  = (const float*)d_in[11];
    const float* bhn  = (const float*)d_in[12];

    ull* s0 = (ull*)d_ws;          // 2048 slots/buffer, no init needed
    ull* s1 = s0 + HDIM;

    gru_all<<<NBLK, NTHR, 0, stream>>>(x, We, be, Wir, bir, Wiz, biz, Win, bin_,
                                       Whr, Whz, Whn, bhn,
                                       (float*)d_out, s0, s1);
}